// Round 9
// baseline (172.819 us; speedup 1.0000x reference)
//
#include <hip/hip_runtime.h>
#include <hip/hip_bf16.h>

typedef unsigned int u32;
typedef unsigned short u16;
typedef __attribute__((ext_vector_type(8))) __bf16 bf8v;
typedef __attribute__((ext_vector_type(16))) float f32x16;
typedef __attribute__((ext_vector_type(8))) u16 u16x8;

// float -> bf16 round-to-nearest-even
__device__ inline u16 f2bf(float f) {
    u32 u = __float_as_uint(f);
    u = (u + 0x7FFF + ((u >> 16) & 1)) >> 16;
    return (u16)u;
}
__device__ inline float bf2f(u16 h) { return __uint_as_float(((u32)h) << 16); }

// packed bf16 pair from two f32 (hardware RNE; identical rounding to f2bf)
__device__ inline u32 cvtpk(float a, float b) {
    u32 r;
    asm("v_cvt_pk_bf16_f32 %0, %1, %2" : "=v"(r) : "v"(a), "v"(b));
    return r;
}
// exchange: a[lanes 32-63] <-> b[lanes 0-31]
__device__ inline void plswap(u32& a, u32& b) {
    asm("v_permlane32_swap_b32 %0, %1" : "+v"(a), "+v"(b));
}

// async global->LDS DMA, 16B/lane; LDS dest = wave-uniform base + lane*16
__device__ inline void dma16(const u16* g, u16* l) {
    __builtin_amdgcn_global_load_lds(
        (const __attribute__((address_space(1))) void*)g,
        (__attribute__((address_space(3))) void*)l, 16, 0, 0);
}

// ---------------- QKV projection with inline fp32->bf16 conversion ----------
// grid 768 (3 blocks/CU, XCD-aware), block 256 = 4 waves x 32 rows.
// cvt_all is FOLDED IN (code proven in the R5/R6 fused phase 1): W staged
// fp32 -> cvt -> chunk-XOR-swizzled ds_write; x A-frags converted in-register
// per kk. No xp/wall intermediates, one fewer dispatch.
// Q/K use SWAPPED MFMA operands (mfma(W,x)): reg-quad holds 4 consecutive
// out-cols -> cvtpk x2 + 8-B store, wave-contiguous. V keeps (x,W) order
// (its layout has R&7 = 4*l5+i -> same quad vectorization).
// Q pre-scaled by log2e/scale.
// Q,K packed: [t=n/32][c=d/8][n%32][8];  V packed: [t][kvc=(n%32)/8][d][n%8]
__global__ __launch_bounds__(256) void qkv_proj(
    const float* __restrict__ x,
    const float* __restrict__ wq, const float* __restrict__ bq,
    const float* __restrict__ wk, const float* __restrict__ bk,
    const float* __restrict__ wv, const float* __restrict__ bv,
    const float* __restrict__ scale,
    u16* __restrict__ qp, u16* __restrict__ kp, u16* __restrict__ vp)
{
    __shared__ u16 Ws[128 * 256];   // 64 KB W tile, rows chunk-XOR-swizzled

    const int blk = blockIdx.x;
    const int xcd = blk & 7;
    const int r2 = blk >> 3;            // 0..95
    const int rt = r2 / 6;              // 0..15
    const int cz = r2 % 6;
    const int sel = cz >> 1;            // 0..2
    const int colbase = (cz & 1) * 128;
    const int rowbase0 = (xcd * 16 + rt) * 128;   // disjoint 2048-row slab per XCD

    const float* wsrc = sel == 0 ? wq : sel == 1 ? wk : wv;
    const float* bias = sel == 0 ? bq : sel == 1 ? bk : bv;
    const float qs = sel == 0 ? 1.44269504088896f / scale[0] : 1.0f;  // log2e/scale into Q
    const int tid = threadIdx.x;
    const int wave = tid >> 6, lane = tid & 63;
    const int l31 = lane & 31, l5 = lane >> 5;
    const int tg = (rowbase0 >> 5) + wave;        // global 32-row tile index

    // stage W rows [colbase, +128): fp32 load -> cvt -> swizzled ds_write
    // LDS image: Ws[r][ (c ^ (r&7)) * 8 ]  (conflict-free swizzled reads)
    {
#pragma unroll
        for (int j = 0; j < 16; j++) {
            const int g = j * 256 + tid;
            const int r = g >> 5, c = g & 31;
            const float* sp = wsrc + (colbase + r) * 256 + c * 8;
            float4 a = *(const float4*)sp;
            float4 b = *(const float4*)(sp + 4);
            uint4 o;
            o.x = cvtpk(a.x, a.y); o.y = cvtpk(a.z, a.w);
            o.z = cvtpk(b.x, b.y); o.w = cvtpk(b.z, b.w);
            *(uint4*)(Ws + r * 256 + ((c ^ (r & 7)) * 8)) = o;
        }
    }
    __syncthreads();

    f32x16 acc[4];
#pragma unroll
    for (int cb = 0; cb < 4; cb++)
#pragma unroll
        for (int j = 0; j < 16; j++) acc[cb][j] = 0.f;

    // A-frags: convert x fp32 -> bf16 in-register (RNE, identical to old cvt)
    const float* xrow = x + (size_t)(tg * 32 + l31) * 256;
    const int sw = l31 & 7;
    if (sel < 2) {
        // swapped: D[row=out-col][col=n(l31)]
#pragma unroll
        for (int kk = 0; kk < 16; kk++) {
            const float* sp = xrow + (kk * 2 + l5) * 8;
            float4 a = *(const float4*)sp;
            float4 b = *(const float4*)(sp + 4);
            union { uint4 u; bf8v v; } afu;
            afu.u.x = cvtpk(a.x, a.y); afu.u.y = cvtpk(a.z, a.w);
            afu.u.z = cvtpk(b.x, b.y); afu.u.w = cvtpk(b.z, b.w);
            const bf8v af = afu.v;
            const int co = ((kk * 2 + l5) ^ sw) * 8;
#pragma unroll
            for (int cb = 0; cb < 4; cb++) {
                bf8v bfr = *(const bf8v*)(Ws + (cb * 32 + l31) * 256 + co);
                acc[cb] = __builtin_amdgcn_mfma_f32_32x32x16_bf16(bfr, af, acc[cb], 0, 0, 0);
            }
        }
        // epilogue: lane=n-row l31; reg r=4q+i -> col e = colb + 8q + 4*l5 + i
        u16* base = (sel == 0 ? qp : kp) + tg * 8192;
#pragma unroll
        for (int cb = 0; cb < 4; cb++) {
            const int colb = colbase + cb * 32;
#pragma unroll
            for (int q = 0; q < 4; q++) {
                const float4 b4 = *(const float4*)(bias + colb + 8 * q + 4 * l5);
                const float v0 = (acc[cb][4 * q + 0] + b4.x) * qs;
                const float v1 = (acc[cb][4 * q + 1] + b4.y) * qs;
                const float v2 = (acc[cb][4 * q + 2] + b4.z) * qs;
                const float v3 = (acc[cb][4 * q + 3] + b4.w) * qs;
                uint2 o2 = { cvtpk(v0, v1), cvtpk(v2, v3) };
                *(uint2*)(base + ((colb >> 3) + q) * 256 + l31 * 8 + 4 * l5) = o2;
            }
        }
    } else {
        // V: original order, D[row=n(R)][col=d(l31)]
#pragma unroll
        for (int kk = 0; kk < 16; kk++) {
            const float* sp = xrow + (kk * 2 + l5) * 8;
            float4 a = *(const float4*)sp;
            float4 b = *(const float4*)(sp + 4);
            union { uint4 u; bf8v v; } afu;
            afu.u.x = cvtpk(a.x, a.y); afu.u.y = cvtpk(a.z, a.w);
            afu.u.z = cvtpk(b.x, b.y); afu.u.w = cvtpk(b.z, b.w);
            const bf8v af = afu.v;
            const int co = ((kk * 2 + l5) ^ sw) * 8;
#pragma unroll
            for (int cb = 0; cb < 4; cb++) {
                bf8v bfr = *(const bf8v*)(Ws + (cb * 32 + l31) * 256 + co);
                acc[cb] = __builtin_amdgcn_mfma_f32_32x32x16_bf16(af, bfr, acc[cb], 0, 0, 0);
            }
        }
        // epilogue: reg r=4q+i -> n-row R = 8q + 4*l5 + i -> q*2048 + d0*8 + 4*l5 + i
        u16* base = vp + tg * 8192;
#pragma unroll
        for (int cb = 0; cb < 4; cb++) {
            const int colb = colbase + cb * 32;
            const float bc = bias[colb + l31];
            const int d0 = colb + l31;
#pragma unroll
            for (int q = 0; q < 4; q++) {
                const float v0 = acc[cb][4 * q + 0] + bc;
                const float v1 = acc[cb][4 * q + 1] + bc;
                const float v2 = acc[cb][4 * q + 2] + bc;
                const float v3 = acc[cb][4 * q + 3] + bc;
                uint2 o2 = { cvtpk(v0, v1), cvtpk(v2, v3) };
                *(uint2*)(base + q * 2048 + d0 * 8 + 4 * l5) = o2;
            }
        }
    }
}

// ---------------- flash attention: phase-fused MFMA pipeline, in-register P ----
// grid 512 (XCD-swizzled), block 256 = 4 waves x 32 q-rows. Bc=32, D=256, S=4.
// Q arrives pre-scaled by log2e/scale, so P = exp2(c0+c1) directly.
// Per iter: [vmcnt(0); barrier; DMA V(it+1),K(it+2) at prio 0];
//   setprio(1): phase A QK(it+1) swapped dual 8-deep chains; phase B PV(it)
//   16 MFMAs source-interleaved with exp2 of P(it+1); setprio(0).
//   With 2 independent blocks/CU at different phases, prio-1 MFMA regions win
//   arbitration over the sibling block's prio-0 VALU tail (T5 regime).
//   l-sum: VALU tree (replaces ls-MFMAs); partner half added at epilogue.
//   tail: 8 cvt_pk + 4 permlane32_swap rebuild pf0/pf1 A-frags in-register.
// K prefetched 2 ahead, V 1 ahead; 1 barrier/iter.
__global__ __launch_bounds__(256, 2) void flash_attn(
    const u16* __restrict__ qp_, const u16* __restrict__ kp_, const u16* __restrict__ vp_,
    u16* __restrict__ Opb, float* __restrict__ ml)
{
    __shared__ u16 Ks[2 * 8192];   // [buf][c(32)][kv(32)][8]
    __shared__ u16 Vs[2 * 8192];   // [buf][kvc(4)][d(256)][8]

    const int tid = threadIdx.x;
    const int wave = tid >> 6, lane = tid & 63;
    const int l31 = lane & 31, l5 = lane >> 5;

    const int blk = blockIdx.x;
    const int slot = blk >> 3;
    const int g = (blk & 7) * 2 + (slot >> 5);   // (b,s) group; matches proj's XCD slabs
    const int qtile = slot & 31;
    const int b = g >> 2, s = g & 3;
    const int qbase = qtile * 128 + wave * 32;

    // Q frags from packed layout (coalesced); used as MFMA *B* operand (same
    // register layout as A: lane -> (index=l31, k=8*l5+j))
    bf8v qf[16];
    {
        const u16* qp = qp_ + (b * 128 + qtile * 4 + wave) * 8192 + l31 * 8;
#pragma unroll
        for (int kk = 0; kk < 16; kk++)
            qf[kk] = *(const bf8v*)(qp + (kk * 2 + l5) * 256);
    }

    f32x16 o[8];
#pragma unroll
    for (int i = 0; i < 8; i++)
#pragma unroll
        for (int j = 0; j < 16; j++) o[i][j] = 0.f;
    float lsum = 0.f;

    const u16* kbase = kp_ + (b * 128 + s * 32) * 8192;
    const u16* vbase = vp_ + (b * 128 + s * 32) * 8192;

    // prologue: K0 (all 4 chunks FIRST so vmcnt(8) == K0 landed), then V0, K1
#pragma unroll
    for (int j = 0; j < 4; j++) {
        const int i = wave * 4 + j;
        dma16(kbase + i * 512 + lane * 8, Ks + i * 512);
    }
#pragma unroll
    for (int j = 0; j < 4; j++) {
        const int i = wave * 4 + j;
        dma16(vbase + i * 512 + lane * 8, Vs + i * 512);
    }
#pragma unroll
    for (int j = 0; j < 4; j++) {
        const int i = wave * 4 + j;
        dma16(kbase + 8192 + i * 512 + lane * 8, Ks + 8192 + i * 512);
    }
    asm volatile("s_waitcnt vmcnt(8)" ::: "memory");
    asm volatile("s_barrier" ::: "memory");

    // QK(0) swapped -> P(0) A-frags in-register
    bf8v pf0, pf1;
    {
        f32x16 c0, c1;
#pragma unroll
        for (int j = 0; j < 16; j++) { c0[j] = 0.f; c1[j] = 0.f; }
#pragma unroll
        for (int j = 0; j < 8; j++) {
            bf8v kf0 = *(const bf8v*)(Ks + (j * 2 + l5) * 256 + l31 * 8);
            c0 = __builtin_amdgcn_mfma_f32_32x32x16_bf16(kf0, qf[j], c0, 0, 0, 0);
            bf8v kf1 = *(const bf8v*)(Ks + ((8 + j) * 2 + l5) * 256 + l31 * 8);
            c1 = __builtin_amdgcn_mfma_f32_32x32x16_bf16(kf1, qf[8 + j], c1, 0, 0, 0);
        }
        float e[16];
#pragma unroll
        for (int r = 0; r < 16; r++)
            e[r] = __builtin_amdgcn_exp2f(c0[r] + c1[r]);
        {
            float s0 = (e[0] + e[1]) + (e[2] + e[3]);
            float s1 = (e[4] + e[5]) + (e[6] + e[7]);
            float s2 = (e[8] + e[9]) + (e[10] + e[11]);
            float s3 = (e[12] + e[13]) + (e[14] + e[15]);
            lsum += (s0 + s1) + (s2 + s3);
        }
        u32 pA = cvtpk(e[0], e[1]), pB = cvtpk(e[2], e[3]);
        u32 pC = cvtpk(e[4], e[5]), pD = cvtpk(e[6], e[7]);
        plswap(pA, pC); plswap(pB, pD);
        u32 pE = cvtpk(e[8], e[9]),  pF = cvtpk(e[10], e[11]);
        u32 pG = cvtpk(e[12], e[13]), pH = cvtpk(e[14], e[15]);
        plswap(pE, pG); plswap(pF, pH);
        union { uint4 u; bf8v v; } u0, u1;
        u0.u = (uint4){pA, pB, pC, pD};
        u1.u = (uint4){pE, pF, pG, pH};
        pf0 = u0.v; pf1 = u1.v;
    }

#pragma unroll 1
    for (int it = 0; it < 31; it++) {
        const int buf = it & 1;
        asm volatile("s_waitcnt vmcnt(0)" ::: "memory");  // V(it), K(it+1) landed
        asm volatile("s_barrier" ::: "memory");           // visible; old bufs free
        {
            const u16* vt_ = vbase + (it + 1) * 8192;
#pragma unroll
            for (int j = 0; j < 4; j++) {
                const int i = wave * 4 + j;
                dma16(vt_ + i * 512 + lane * 8, Vs + (buf ^ 1) * 8192 + i * 512);
            }
            if (it < 30) {
                const u16* kt_ = kbase + (it + 2) * 8192;
#pragma unroll
                for (int j = 0; j < 4; j++) {
                    const int i = wave * 4 + j;
                    dma16(kt_ + i * 512 + lane * 8, Ks + buf * 8192 + i * 512);
                }
            }
        }
        // ---- phase A: QK(it+1) swapped, dual 8-deep accumulator chains
        __builtin_amdgcn_s_setprio(1);
        const u16* Kb_ = Ks + (buf ^ 1) * 8192;
        f32x16 c0, c1;
#pragma unroll
        for (int j = 0; j < 16; j++) { c0[j] = 0.f; c1[j] = 0.f; }
#pragma unroll
        for (int j = 0; j < 8; j++) {
            bf8v kf0 = *(const bf8v*)(Kb_ + (j * 2 + l5) * 256 + l31 * 8);
            c0 = __builtin_amdgcn_mfma_f32_32x32x16_bf16(kf0, qf[j], c0, 0, 0, 0);
            bf8v kf1 = *(const bf8v*)(Kb_ + ((8 + j) * 2 + l5) * 256 + l31 * 8);
            c1 = __builtin_amdgcn_mfma_f32_32x32x16_bf16(kf1, qf[8 + j], c1, 0, 0, 0);
        }
        // ---- phase B: PV(it) MFMAs interleaved with exp2 of P(it+1)
        const u16* Vb_ = Vs + buf * 8192;
        float e[16];
#pragma unroll
        for (int j = 0; j < 8; j++) {
            bf8v vf0 = *(const bf8v*)(Vb_ + (l5 * 256 + j * 32 + l31) * 8);
            o[j] = __builtin_amdgcn_mfma_f32_32x32x16_bf16(pf0, vf0, o[j], 0, 0, 0);
            e[2 * j] = __builtin_amdgcn_exp2f(c0[2 * j] + c1[2 * j]);
            bf8v vf1 = *(const bf8v*)(Vb_ + ((2 + l5) * 256 + j * 32 + l31) * 8);
            o[j] = __builtin_amdgcn_mfma_f32_32x32x16_bf16(pf1, vf1, o[j], 0, 0, 0);
            e[2 * j + 1] = __builtin_amdgcn_exp2f(c0[2 * j + 1] + c1[2 * j + 1]);
        }
        __builtin_amdgcn_s_setprio(0);
        // l-sum of P(it+1) in VALU (replaces 2 ls-MFMAs), prio 0
        {
            float s0 = (e[0] + e[1]) + (e[2] + e[3]);
            float s1 = (e[4] + e[5]) + (e[6] + e[7]);
            float s2 = (e[8] + e[9]) + (e[10] + e[11]);
            float s3 = (e[12] + e[13]) + (e[14] + e[15]);
            lsum += (s0 + s1) + (s2 + s3);
        }
        // ---- tail: build P(it+1) A-frags in-register (no LDS roundtrip)
        {
            u32 pA = cvtpk(e[0], e[1]), pB = cvtpk(e[2], e[3]);
            u32 pC = cvtpk(e[4], e[5]), pD = cvtpk(e[6], e[7]);
            plswap(pA, pC); plswap(pB, pD);
            u32 pE = cvtpk(e[8], e[9]),  pF = cvtpk(e[10], e[11]);
            u32 pG = cvtpk(e[12], e[13]), pH = cvtpk(e[14], e[15]);
            plswap(pE, pG); plswap(pF, pH);
            union { uint4 u; bf8v v; } u0, u1;
            u0.u = (uint4){pA, pB, pC, pD};
            u1.u = (uint4){pE, pF, pG, pH};
            pf0 = u0.v; pf1 = u1.v;
        }
    }

    // tail: PV(31)
    asm volatile("s_waitcnt vmcnt(0)" ::: "memory");
    asm volatile("s_barrier" ::: "memory");
    {
        const u16* Vb_ = Vs + 8192;   // V(31) in buf 1
        __builtin_amdgcn_s_setprio(1);
#pragma unroll
        for (int j = 0; j < 8; j++) {
            bf8v vf0 = *(const bf8v*)(Vb_ + (l5 * 256 + j * 32 + l31) * 8);
            o[j] = __builtin_amdgcn_mfma_f32_32x32x16_bf16(pf0, vf0, o[j], 0, 0, 0);
            bf8v vf1 = *(const bf8v*)(Vb_ + ((2 + l5) * 256 + j * 32 + l31) * 8);
            o[j] = __builtin_amdgcn_mfma_f32_32x32x16_bf16(pf1, vf1, o[j], 0, 0, 0);
        }
        __builtin_amdgcn_s_setprio(0);
    }

    // epilogue: unnormalized O in bf16 + l (m==0 everywhere)
    const int rowg = s * 16384 + b * 4096 + qbase;
    u16* ob = Opb + (size_t)rowg * 256;
#pragma unroll
    for (int nb = 0; nb < 8; nb++)
#pragma unroll
        for (int r = 0; r < 16; r++) {
            const int R = (r & 3) + 8 * (r >> 2) + 4 * l5;
            ob[R * 256 + nb * 32 + l31] = f2bf(o[nb][r]);
        }
    // l: add partner half-lane (lane +-32) via permlane32_swap, write per q-row
    {
        u32 a = __float_as_uint(lsum), b2 = a;
        plswap(a, b2);
        const float tot = lsum + __uint_as_float(l5 ? a : b2);
        if (l5 == 0) ml[rowg + l31] = tot;
    }
}

// ---------------- combine partials (m==0: denom = sum of l) ----------------
__global__ __launch_bounds__(256) void combine(
    const u16* __restrict__ Opb, const float* __restrict__ ml, float* __restrict__ out)
{
    const int row = blockIdx.x * 4 + (threadIdx.x >> 6);
    const int lane = threadIdx.x & 63;
    const float denom = ml[row] + ml[16384 + row] + ml[32768 + row] + ml[49152 + row];
    float4 acc = {0.f, 0.f, 0.f, 0.f};
#pragma unroll
    for (int si = 0; si < 4; si++) {
        ushort4 v = *(const ushort4*)(Opb + ((size_t)si * 16384 + row) * 256 + lane * 4);
        acc.x += bf2f(v.x); acc.y += bf2f(v.y);
        acc.z += bf2f(v.z); acc.w += bf2f(v.w);
    }
    const float inv = 1.0f / denom;
    acc.x *= inv; acc.y *= inv; acc.z *= inv; acc.w *= inv;
    *((float4*)(out + (size_t)row * 256) + lane) = acc;
}

extern "C" void kernel_launch(void* const* d_in, const int* in_sizes, int n_in,
                              void* d_out, int out_size, void* d_ws, size_t ws_size,
                              hipStream_t stream) {
    const float* x     = (const float*)d_in[0];
    const float* Wq    = (const float*)d_in[1];
    const float* bq    = (const float*)d_in[2];
    const float* Wk    = (const float*)d_in[3];
    const float* bk    = (const float*)d_in[4];
    const float* Wv    = (const float*)d_in[5];
    const float* bv    = (const float*)d_in[6];
    const float* scale = (const float*)d_in[7];
    float* out = (float*)d_out;

    char* ws = (char*)d_ws;
    u16* qp   = (u16*)ws;                        // 8 MB packed Q (pre-scaled)
    u16* kp   = (u16*)(ws + (8u  << 20));        // 8 MB packed K
    u16* vp   = (u16*)(ws + (16u << 20));        // 8 MB packed V
    u16* Opb  = (u16*)(ws + (24u << 20));        // 4 x 8 MB bf16 partials
    float* ml = (float*)(ws + (56u << 20));      // 4 x 64 KB l-sums

    qkv_proj<<<768, 256, 0, stream>>>(x, Wq, bq, Wk, bk, Wv, bv, scale, qp, kp, vp);
    flash_attn<<<512, 256, 0, stream>>>(qp, kp, vp, Opb, ml);
    combine<<<4096, 256, 0, stream>>>(Opb, ml, out);
}

// Round 10
// 167.901 us; speedup vs baseline: 1.0293x; 1.0293x over previous
//
#include <hip/hip_runtime.h>
#include <hip/hip_bf16.h>

typedef unsigned int u32;
typedef unsigned short u16;
typedef __attribute__((ext_vector_type(8))) __bf16 bf8v;
typedef __attribute__((ext_vector_type(16))) float f32x16;
typedef __attribute__((ext_vector_type(8))) u16 u16x8;

// float -> bf16 round-to-nearest-even
__device__ inline u16 f2bf(float f) {
    u32 u = __float_as_uint(f);
    u = (u + 0x7FFF + ((u >> 16) & 1)) >> 16;
    return (u16)u;
}
__device__ inline u32 pk2(float a, float b) {
    return (u32)f2bf(a) | ((u32)f2bf(b) << 16);
}
__device__ inline float bf2f(u16 h) { return __uint_as_float(((u32)h) << 16); }

// packed bf16 pair from two f32 (hardware RNE; identical rounding to f2bf)
__device__ inline u32 cvtpk(float a, float b) {
    u32 r;
    asm("v_cvt_pk_bf16_f32 %0, %1, %2" : "=v"(r) : "v"(a), "v"(b));
    return r;
}
// exchange: a[lanes 32-63] <-> b[lanes 0-31]
__device__ inline void plswap(u32& a, u32& b) {
    asm("v_permlane32_swap_b32 %0, %1" : "+v"(a), "+v"(b));
}

// async global->LDS DMA, 16B/lane; LDS dest = wave-uniform base + lane*16
__device__ inline void dma16(const u16* g, u16* l) {
    __builtin_amdgcn_global_load_lds(
        (const __attribute__((address_space(1))) void*)g,
        (__attribute__((address_space(3))) void*)l, 16, 0, 0);
}

// ---------------- fused input conversion ----------------
// blk < 2048: x fp32 -> packed tiles xp[t=row/32][c=d/8][row%32][8]
// blk >= 2048: W fp32 -> bf16, chunk-XOR-swizzled rows:
//   wall[m][row][cs=c^(row&7)][8]  (so LDS-linear DMA + conflict-free ds_read)
__global__ void cvt_all(const float* __restrict__ x,
                        const float* __restrict__ wq, const float* __restrict__ wk,
                        const float* __restrict__ wv,
                        u16* __restrict__ xp, u16* __restrict__ wall) {
    const int blk = blockIdx.x;
    if (blk < 2048) {
        int g = blk * 256 + threadIdx.x;
        int row = g >> 5, cp = g & 31;
        const float* s = x + row * 256 + cp * 8;
        float4 a = *(const float4*)s;
        float4 b = *(const float4*)(s + 4);
        uint4 o;
        o.x = pk2(a.x, a.y); o.y = pk2(a.z, a.w);
        o.z = pk2(b.x, b.y); o.w = pk2(b.z, b.w);
        *(uint4*)(xp + (row >> 5) * 8192 + cp * 256 + (row & 31) * 8) = o;
    } else {
        const int bb = blk - 2048;                 // 0..95
        const int m = bb >> 5;
        const float* src = m == 0 ? wq : m == 1 ? wk : wv;
        int g = (bb & 31) * 256 + threadIdx.x;
        int row = g >> 5, c = g & 31;
        const float* s = src + row * 256 + c * 8;
        float4 a = *(const float4*)s;
        float4 b = *(const float4*)(s + 4);
        uint4 o;
        o.x = pk2(a.x, a.y); o.y = pk2(a.z, a.w);
        o.z = pk2(b.x, b.y); o.w = pk2(b.z, b.w);
        *(uint4*)(wall + m * 65536 + row * 256 + ((c ^ (row & 7)) * 8)) = o;
    }
}

// ---------------- QKV projection: 32x32 MFMA, 128-col W tile in LDS ----------
// grid 768 (3 blocks/CU, XCD-aware), block 256 = 4 waves x 32 rows.
// Q/K use SWAPPED MFMA operands (mfma(W,x)): reg-quad holds 4 consecutive
// out-cols -> cvtpk x2 + one 8-B store, wave-contiguous 512 B. V keeps (x,W)
// order (R&7 = 4*l5+i -> same quad vectorization). Q pre-scaled log2e/scale.
// Q,K packed: [t=n/32][c=d/8][n%32][8];  V packed: [t][kvc=(n%32)/8][d][n%8]
__global__ __launch_bounds__(256) void qkv_proj(
    const u16* __restrict__ xp, const u16* __restrict__ wall,
    const float* __restrict__ bq, const float* __restrict__ bk, const float* __restrict__ bv,
    const float* __restrict__ scale,
    u16* __restrict__ qp, u16* __restrict__ kp, u16* __restrict__ vp)
{
    __shared__ u16 Ws[128 * 256];   // 64 KB W tile, rows chunk-XOR-swizzled

    const int blk = blockIdx.x;
    const int xcd = blk & 7;
    const int r2 = blk >> 3;            // 0..95
    const int rt = r2 / 6;              // 0..15
    const int cz = r2 % 6;
    const int sel = cz >> 1;            // 0..2
    const int colbase = (cz & 1) * 128;
    const int rowbase0 = (xcd * 16 + rt) * 128;   // disjoint 2048-row slab per XCD

    const float* bias = sel == 0 ? bq : sel == 1 ? bk : bv;
    const float qs = sel == 0 ? 1.44269504088896f / scale[0] : 1.0f;  // log2e/scale into Q
    const int tid = threadIdx.x;
    const int wave = tid >> 6, lane = tid & 63;
    const int l31 = lane & 31, l5 = lane >> 5;
    const int tg = (rowbase0 >> 5) + wave;        // global 32-row tile index

    // stage W rows [colbase, +128) -> LDS (linear DMA, swizzle pre-applied)
    {
        const u16* wsrc = wall + sel * 65536 + colbase * 256;
#pragma unroll
        for (int j = 0; j < 16; j++) {
            const int i = wave * 16 + j;           // 64 x 1KB chunks
            dma16(wsrc + i * 512 + lane * 8, Ws + i * 512);
        }
    }
    asm volatile("s_waitcnt vmcnt(0)" ::: "memory");
    __syncthreads();

    f32x16 acc[4];
#pragma unroll
    for (int cb = 0; cb < 4; cb++)
#pragma unroll
        for (int j = 0; j < 16; j++) acc[cb][j] = 0.f;

    const u16* ap = xp + tg * 8192 + l5 * 256 + l31 * 8;     // coalesced 1KB/instr
    const int sw = l31 & 7;
    if (sel < 2) {
        // swapped: D[row=out-col(R)][col=n(l31)]
#pragma unroll
        for (int kk = 0; kk < 16; kk++) {
            bf8v af = *(const bf8v*)(ap + kk * 512);
            const int co = ((kk * 2 + l5) ^ sw) * 8;
#pragma unroll
            for (int cb = 0; cb < 4; cb++) {
                bf8v bfr = *(const bf8v*)(Ws + (cb * 32 + l31) * 256 + co);
                acc[cb] = __builtin_amdgcn_mfma_f32_32x32x16_bf16(bfr, af, acc[cb], 0, 0, 0);
            }
        }
        // epilogue: lane=n-row l31; reg r=4q+i -> col e = colb + 8q + 4*l5 + i
        u16* base = (sel == 0 ? qp : kp) + tg * 8192;
#pragma unroll
        for (int cb = 0; cb < 4; cb++) {
            const int colb = colbase + cb * 32;
#pragma unroll
            for (int q = 0; q < 4; q++) {
                const float4 b4 = *(const float4*)(bias + colb + 8 * q + 4 * l5);
                const float v0 = (acc[cb][4 * q + 0] + b4.x) * qs;
                const float v1 = (acc[cb][4 * q + 1] + b4.y) * qs;
                const float v2 = (acc[cb][4 * q + 2] + b4.z) * qs;
                const float v3 = (acc[cb][4 * q + 3] + b4.w) * qs;
                uint2 o2 = { cvtpk(v0, v1), cvtpk(v2, v3) };
                *(uint2*)(base + ((colb >> 3) + q) * 256 + l31 * 8 + 4 * l5) = o2;
            }
        }
    } else {
        // V: original order, D[row=n(R)][col=d(l31)]
#pragma unroll
        for (int kk = 0; kk < 16; kk++) {
            bf8v af = *(const bf8v*)(ap + kk * 512);
            const int co = ((kk * 2 + l5) ^ sw) * 8;
#pragma unroll
            for (int cb = 0; cb < 4; cb++) {
                bf8v bfr = *(const bf8v*)(Ws + (cb * 32 + l31) * 256 + co);
                acc[cb] = __builtin_amdgcn_mfma_f32_32x32x16_bf16(af, bfr, acc[cb], 0, 0, 0);
            }
        }
        // epilogue: reg r=4q+i -> n-row R = 8q + 4*l5 + i -> q*2048 + d0*8 + 4*l5 + i
        u16* base = vp + tg * 8192;
#pragma unroll
        for (int cb = 0; cb < 4; cb++) {
            const int colb = colbase + cb * 32;
            const float bc = bias[colb + l31];
            const int d0 = colb + l31;
#pragma unroll
            for (int q = 0; q < 4; q++) {
                const float v0 = acc[cb][4 * q + 0] + bc;
                const float v1 = acc[cb][4 * q + 1] + bc;
                const float v2 = acc[cb][4 * q + 2] + bc;
                const float v3 = acc[cb][4 * q + 3] + bc;
                uint2 o2 = { cvtpk(v0, v1), cvtpk(v2, v3) };
                *(uint2*)(base + q * 2048 + d0 * 8 + 4 * l5) = o2;
            }
        }
    }
}

// ---------------- flash attention: phase-fused MFMA pipeline, in-register P ----
// grid 512 (XCD-swizzled), block 256 = 4 waves x 32 q-rows. Bc=32, D=256, S=4.
// Q arrives pre-scaled by log2e/scale, so P = exp2(c0+c1) directly.
// Per iter: [vmcnt(0); barrier; DMA V(it+1),K(it+2) at prio 0];
//   setprio(1): phase A QK(it+1) swapped dual 8-deep chains; phase B PV(it)
//   16 MFMAs source-interleaved with exp2 of P(it+1); setprio(0).
//   (T5 regime: 2 independent blocks/CU at different phases.)
//   l-sum: VALU tree (replaces ls-MFMAs); partner half added at epilogue.
//   tail: 8 cvt_pk + 4 permlane32_swap rebuild pf0/pf1 A-frags in-register.
// K prefetched 2 ahead, V 1 ahead; 1 barrier/iter.
__global__ __launch_bounds__(256, 2) void flash_attn(
    const u16* __restrict__ qp_, const u16* __restrict__ kp_, const u16* __restrict__ vp_,
    u16* __restrict__ Opb, float* __restrict__ ml)
{
    __shared__ u16 Ks[2 * 8192];   // [buf][c(32)][kv(32)][8]
    __shared__ u16 Vs[2 * 8192];   // [buf][kvc(4)][d(256)][8]

    const int tid = threadIdx.x;
    const int wave = tid >> 6, lane = tid & 63;
    const int l31 = lane & 31, l5 = lane >> 5;

    const int blk = blockIdx.x;
    const int slot = blk >> 3;
    const int g = (blk & 7) * 2 + (slot >> 5);   // (b,s) group; matches proj's XCD slabs
    const int qtile = slot & 31;
    const int b = g >> 2, s = g & 3;
    const int qbase = qtile * 128 + wave * 32;

    // Q frags from packed layout (coalesced); used as MFMA *B* operand (same
    // register layout as A: lane -> (index=l31, k=8*l5+j))
    bf8v qf[16];
    {
        const u16* qp = qp_ + (b * 128 + qtile * 4 + wave) * 8192 + l31 * 8;
#pragma unroll
        for (int kk = 0; kk < 16; kk++)
            qf[kk] = *(const bf8v*)(qp + (kk * 2 + l5) * 256);
    }

    f32x16 o[8];
#pragma unroll
    for (int i = 0; i < 8; i++)
#pragma unroll
        for (int j = 0; j < 16; j++) o[i][j] = 0.f;
    float lsum = 0.f;

    const u16* kbase = kp_ + (b * 128 + s * 32) * 8192;
    const u16* vbase = vp_ + (b * 128 + s * 32) * 8192;

    // prologue: K0 (all 4 chunks FIRST so vmcnt(8) == K0 landed), then V0, K1
#pragma unroll
    for (int j = 0; j < 4; j++) {
        const int i = wave * 4 + j;
        dma16(kbase + i * 512 + lane * 8, Ks + i * 512);
    }
#pragma unroll
    for (int j = 0; j < 4; j++) {
        const int i = wave * 4 + j;
        dma16(vbase + i * 512 + lane * 8, Vs + i * 512);
    }
#pragma unroll
    for (int j = 0; j < 4; j++) {
        const int i = wave * 4 + j;
        dma16(kbase + 8192 + i * 512 + lane * 8, Ks + 8192 + i * 512);
    }
    asm volatile("s_waitcnt vmcnt(8)" ::: "memory");
    asm volatile("s_barrier" ::: "memory");

    // QK(0) swapped -> P(0) A-frags in-register
    bf8v pf0, pf1;
    {
        f32x16 c0, c1;
#pragma unroll
        for (int j = 0; j < 16; j++) { c0[j] = 0.f; c1[j] = 0.f; }
#pragma unroll
        for (int j = 0; j < 8; j++) {
            bf8v kf0 = *(const bf8v*)(Ks + (j * 2 + l5) * 256 + l31 * 8);
            c0 = __builtin_amdgcn_mfma_f32_32x32x16_bf16(kf0, qf[j], c0, 0, 0, 0);
            bf8v kf1 = *(const bf8v*)(Ks + ((8 + j) * 2 + l5) * 256 + l31 * 8);
            c1 = __builtin_amdgcn_mfma_f32_32x32x16_bf16(kf1, qf[8 + j], c1, 0, 0, 0);
        }
        float e[16];
#pragma unroll
        for (int r = 0; r < 16; r++)
            e[r] = __builtin_amdgcn_exp2f(c0[r] + c1[r]);
        {
            float s0 = (e[0] + e[1]) + (e[2] + e[3]);
            float s1 = (e[4] + e[5]) + (e[6] + e[7]);
            float s2 = (e[8] + e[9]) + (e[10] + e[11]);
            float s3 = (e[12] + e[13]) + (e[14] + e[15]);
            lsum += (s0 + s1) + (s2 + s3);
        }
        u32 pA = cvtpk(e[0], e[1]), pB = cvtpk(e[2], e[3]);
        u32 pC = cvtpk(e[4], e[5]), pD = cvtpk(e[6], e[7]);
        plswap(pA, pC); plswap(pB, pD);
        u32 pE = cvtpk(e[8], e[9]),  pF = cvtpk(e[10], e[11]);
        u32 pG = cvtpk(e[12], e[13]), pH = cvtpk(e[14], e[15]);
        plswap(pE, pG); plswap(pF, pH);
        union { uint4 u; bf8v v; } u0, u1;
        u0.u = (uint4){pA, pB, pC, pD};
        u1.u = (uint4){pE, pF, pG, pH};
        pf0 = u0.v; pf1 = u1.v;
    }

#pragma unroll 1
    for (int it = 0; it < 31; it++) {
        const int buf = it & 1;
        asm volatile("s_waitcnt vmcnt(0)" ::: "memory");  // V(it), K(it+1) landed
        asm volatile("s_barrier" ::: "memory");           // visible; old bufs free
        {
            const u16* vt_ = vbase + (it + 1) * 8192;
#pragma unroll
            for (int j = 0; j < 4; j++) {
                const int i = wave * 4 + j;
                dma16(vt_ + i * 512 + lane * 8, Vs + (buf ^ 1) * 8192 + i * 512);
            }
            if (it < 30) {
                const u16* kt_ = kbase + (it + 2) * 8192;
#pragma unroll
                for (int j = 0; j < 4; j++) {
                    const int i = wave * 4 + j;
                    dma16(kt_ + i * 512 + lane * 8, Ks + buf * 8192 + i * 512);
                }
            }
        }
        // ---- phase A: QK(it+1) swapped, dual 8-deep accumulator chains
        __builtin_amdgcn_s_setprio(1);
        const u16* Kb_ = Ks + (buf ^ 1) * 8192;
        f32x16 c0, c1;
#pragma unroll
        for (int j = 0; j < 16; j++) { c0[j] = 0.f; c1[j] = 0.f; }
#pragma unroll
        for (int j = 0; j < 8; j++) {
            bf8v kf0 = *(const bf8v*)(Kb_ + (j * 2 + l5) * 256 + l31 * 8);
            c0 = __builtin_amdgcn_mfma_f32_32x32x16_bf16(kf0, qf[j], c0, 0, 0, 0);
            bf8v kf1 = *(const bf8v*)(Kb_ + ((8 + j) * 2 + l5) * 256 + l31 * 8);
            c1 = __builtin_amdgcn_mfma_f32_32x32x16_bf16(kf1, qf[8 + j], c1, 0, 0, 0);
        }
        // ---- phase B: PV(it) MFMAs interleaved with exp2 of P(it+1)
        const u16* Vb_ = Vs + buf * 8192;
        float e[16];
#pragma unroll
        for (int j = 0; j < 8; j++) {
            bf8v vf0 = *(const bf8v*)(Vb_ + (l5 * 256 + j * 32 + l31) * 8);
            o[j] = __builtin_amdgcn_mfma_f32_32x32x16_bf16(pf0, vf0, o[j], 0, 0, 0);
            e[2 * j] = __builtin_amdgcn_exp2f(c0[2 * j] + c1[2 * j]);
            bf8v vf1 = *(const bf8v*)(Vb_ + ((2 + l5) * 256 + j * 32 + l31) * 8);
            o[j] = __builtin_amdgcn_mfma_f32_32x32x16_bf16(pf1, vf1, o[j], 0, 0, 0);
            e[2 * j + 1] = __builtin_amdgcn_exp2f(c0[2 * j + 1] + c1[2 * j + 1]);
        }
        __builtin_amdgcn_s_setprio(0);
        // l-sum of P(it+1) in VALU (replaces 2 ls-MFMAs), prio 0
        {
            float s0 = (e[0] + e[1]) + (e[2] + e[3]);
            float s1 = (e[4] + e[5]) + (e[6] + e[7]);
            float s2 = (e[8] + e[9]) + (e[10] + e[11]);
            float s3 = (e[12] + e[13]) + (e[14] + e[15]);
            lsum += (s0 + s1) + (s2 + s3);
        }
        // ---- tail: build P(it+1) A-frags in-register (no LDS roundtrip)
        {
            u32 pA = cvtpk(e[0], e[1]), pB = cvtpk(e[2], e[3]);
            u32 pC = cvtpk(e[4], e[5]), pD = cvtpk(e[6], e[7]);
            plswap(pA, pC); plswap(pB, pD);
            u32 pE = cvtpk(e[8], e[9]),  pF = cvtpk(e[10], e[11]);
            u32 pG = cvtpk(e[12], e[13]), pH = cvtpk(e[14], e[15]);
            plswap(pE, pG); plswap(pF, pH);
            union { uint4 u; bf8v v; } u0, u1;
            u0.u = (uint4){pA, pB, pC, pD};
            u1.u = (uint4){pE, pF, pG, pH};
            pf0 = u0.v; pf1 = u1.v;
        }
    }

    // tail: PV(31)
    asm volatile("s_waitcnt vmcnt(0)" ::: "memory");
    asm volatile("s_barrier" ::: "memory");
    {
        const u16* Vb_ = Vs + 8192;   // V(31) in buf 1
        __builtin_amdgcn_s_setprio(1);
#pragma unroll
        for (int j = 0; j < 8; j++) {
            bf8v vf0 = *(const bf8v*)(Vb_ + (l5 * 256 + j * 32 + l31) * 8);
            o[j] = __builtin_amdgcn_mfma_f32_32x32x16_bf16(pf0, vf0, o[j], 0, 0, 0);
            bf8v vf1 = *(const bf8v*)(Vb_ + ((2 + l5) * 256 + j * 32 + l31) * 8);
            o[j] = __builtin_amdgcn_mfma_f32_32x32x16_bf16(pf1, vf1, o[j], 0, 0, 0);
        }
        __builtin_amdgcn_s_setprio(0);
    }

    // epilogue: unnormalized O in bf16 + l (m==0 everywhere)
    const int rowg = s * 16384 + b * 4096 + qbase;
    u16* ob = Opb + (size_t)rowg * 256;
#pragma unroll
    for (int nb = 0; nb < 8; nb++)
#pragma unroll
        for (int r = 0; r < 16; r++) {
            const int R = (r & 3) + 8 * (r >> 2) + 4 * l5;
            ob[R * 256 + nb * 32 + l31] = f2bf(o[nb][r]);
        }
    // l: add partner half-lane (lane +-32) via permlane32_swap, write per q-row
    {
        u32 a = __float_as_uint(lsum), b2 = a;
        plswap(a, b2);
        const float tot = lsum + __uint_as_float(l5 ? a : b2);
        if (l5 == 0) ml[rowg + l31] = tot;
    }
}

// ---------------- combine partials (m==0: denom = sum of l) ----------------
// grid 2048, block 256 = 8 rows/block; 16 B/lane loads (uint4 = 8 bf16).
__global__ __launch_bounds__(256) void combine(
    const u16* __restrict__ Opb, const float* __restrict__ ml, float* __restrict__ out)
{
    const int row = blockIdx.x * 8 + (threadIdx.x >> 5);
    const int l32 = threadIdx.x & 31;
    const float denom = ml[row] + ml[16384 + row] + ml[32768 + row] + ml[49152 + row];
    float a0 = 0.f, a1 = 0.f, a2 = 0.f, a3 = 0.f, a4 = 0.f, a5 = 0.f, a6 = 0.f, a7 = 0.f;
#pragma unroll
    for (int si = 0; si < 4; si++) {
        u16x8 v = *(const u16x8*)(Opb + ((size_t)si * 16384 + row) * 256 + l32 * 8);
        a0 += bf2f(v[0]); a1 += bf2f(v[1]); a2 += bf2f(v[2]); a3 += bf2f(v[3]);
        a4 += bf2f(v[4]); a5 += bf2f(v[5]); a6 += bf2f(v[6]); a7 += bf2f(v[7]);
    }
    const float inv = 1.0f / denom;
    float4 o0 = { a0 * inv, a1 * inv, a2 * inv, a3 * inv };
    float4 o1 = { a4 * inv, a5 * inv, a6 * inv, a7 * inv };
    float* op = out + (size_t)row * 256 + l32 * 8;
    *(float4*)op = o0;
    *(float4*)(op + 4) = o1;
}

extern "C" void kernel_launch(void* const* d_in, const int* in_sizes, int n_in,
                              void* d_out, int out_size, void* d_ws, size_t ws_size,
                              hipStream_t stream) {
    const float* x     = (const float*)d_in[0];
    const float* Wq    = (const float*)d_in[1];
    const float* bq    = (const float*)d_in[2];
    const float* Wk    = (const float*)d_in[3];
    const float* bk    = (const float*)d_in[4];
    const float* Wv    = (const float*)d_in[5];
    const float* bv    = (const float*)d_in[6];
    const float* scale = (const float*)d_in[7];
    float* out = (float*)d_out;

    char* ws = (char*)d_ws;
    u16* xp   = (u16*)ws;                        // 8 MB packed x
    u16* qp   = (u16*)(ws + (8u  << 20));        // 8 MB packed Q (pre-scaled)
    u16* kp   = (u16*)(ws + (16u << 20));        // 8 MB packed K
    u16* vp   = (u16*)(ws + (24u << 20));        // 8 MB packed V
    u16* wall = (u16*)(ws + (32u << 20));        // 3 x 128 KB bf16 W (swizzled)
    u16* Opb  = (u16*)(ws + (34u << 20));        // 4 x 8 MB bf16 partials
    float* ml = (float*)(ws + (66u << 20));      // 4 x 64 KB l-sums

    cvt_all<<<2144, 256, 0, stream>>>(x, Wq, Wk, Wv, xp, wall);
    qkv_proj<<<768, 256, 0, stream>>>(xp, wall, bq, bk, bv, scale, qp, kp, vp);
    flash_attn<<<512, 256, 0, stream>>>(qp, kp, vp, Opb, ml);
    combine<<<2048, 256, 0, stream>>>(Opb, ml, out);
}

// Round 12
// 166.560 us; speedup vs baseline: 1.0376x; 1.0080x over previous
//
#include <hip/hip_runtime.h>
#include <hip/hip_bf16.h>

typedef unsigned int u32;
typedef unsigned short u16;
typedef __attribute__((ext_vector_type(8))) __bf16 bf8v;
typedef __attribute__((ext_vector_type(16))) float f32x16;
typedef __attribute__((ext_vector_type(8))) u16 u16x8;

// float -> bf16 round-to-nearest-even
__device__ inline u16 f2bf(float f) {
    u32 u = __float_as_uint(f);
    u = (u + 0x7FFF + ((u >> 16) & 1)) >> 16;
    return (u16)u;
}
__device__ inline u32 pk2(float a, float b) {
    return (u32)f2bf(a) | ((u32)f2bf(b) << 16);
}
__device__ inline float bf2f(u16 h) { return __uint_as_float(((u32)h) << 16); }

// packed bf16 pair from two f32 (hardware RNE; identical rounding to f2bf)
__device__ inline u32 cvtpk(float a, float b) {
    u32 r;
    asm("v_cvt_pk_bf16_f32 %0, %1, %2" : "=v"(r) : "v"(a), "v"(b));
    return r;
}
// exchange: a[lanes 32-63] <-> b[lanes 0-31]
__device__ inline void plswap(u32& a, u32& b) {
    asm("v_permlane32_swap_b32 %0, %1" : "+v"(a), "+v"(b));
}

// async global->LDS DMA, 16B/lane; LDS dest = wave-uniform base + lane*16
__device__ inline void dma16(const u16* g, u16* l) {
    __builtin_amdgcn_global_load_lds(
        (const __attribute__((address_space(1))) void*)g,
        (__attribute__((address_space(3))) void*)l, 16, 0, 0);
}

// ---------------- fused input conversion ----------------
// blk < 2048: x fp32 -> packed tiles xp[t=row/32][c=d/8][row%32][8]
// blk >= 2048: W fp32 -> bf16, chunk-XOR-swizzled rows:
//   wall[m][row][cs=c^(row&7)][8]  (so LDS-linear DMA + conflict-free ds_read)
__global__ void cvt_all(const float* __restrict__ x,
                        const float* __restrict__ wq, const float* __restrict__ wk,
                        const float* __restrict__ wv,
                        u16* __restrict__ xp, u16* __restrict__ wall) {
    const int blk = blockIdx.x;
    if (blk < 2048) {
        int g = blk * 256 + threadIdx.x;
        int row = g >> 5, cp = g & 31;
        const float* s = x + row * 256 + cp * 8;
        float4 a = *(const float4*)s;
        float4 b = *(const float4*)(s + 4);
        uint4 o;
        o.x = pk2(a.x, a.y); o.y = pk2(a.z, a.w);
        o.z = pk2(b.x, b.y); o.w = pk2(b.z, b.w);
        *(uint4*)(xp + (row >> 5) * 8192 + cp * 256 + (row & 31) * 8) = o;
    } else {
        const int bb = blk - 2048;                 // 0..95
        const int m = bb >> 5;
        const float* src = m == 0 ? wq : m == 1 ? wk : wv;
        int g = (bb & 31) * 256 + threadIdx.x;
        int row = g >> 5, c = g & 31;
        const float* s = src + row * 256 + c * 8;
        float4 a = *(const float4*)s;
        float4 b = *(const float4*)(s + 4);
        uint4 o;
        o.x = pk2(a.x, a.y); o.y = pk2(a.z, a.w);
        o.z = pk2(b.x, b.y); o.w = pk2(b.z, b.w);
        *(uint4*)(wall + m * 65536 + row * 256 + ((c ^ (row & 7)) * 8)) = o;
    }
}

// ---------------- QKV projection: 32x32 MFMA, 128-col W tile in LDS ----------
// grid 768 (XCD-aware; 64KB LDS -> 2 blocks/CU resident), block 256 = 4 waves.
// af[16] PREFETCHED UPFRONT: one exposed L3 latency instead of 16 partial
// ones (each af load previously covered by only 4 MFMAs ~128 cyc < latency).
// Q/K use SWAPPED MFMA operands (mfma(W,x)): reg-quad holds 4 consecutive
// out-cols -> cvtpk x2 + one 8-B store, wave-contiguous 512 B. V keeps (x,W)
// order (R&7 = 4*l5+i -> same quad vectorization). Q pre-scaled log2e/scale.
// Q,K packed: [t=n/32][c=d/8][n%32][8];  V packed: [t][kvc=(n%32)/8][d][n%8]
__global__ __launch_bounds__(256) void qkv_proj(
    const u16* __restrict__ xp, const u16* __restrict__ wall,
    const float* __restrict__ bq, const float* __restrict__ bk, const float* __restrict__ bv,
    const float* __restrict__ scale,
    u16* __restrict__ qp, u16* __restrict__ kp, u16* __restrict__ vp)
{
    __shared__ u16 Ws[128 * 256];   // 64 KB W tile, rows chunk-XOR-swizzled

    const int blk = blockIdx.x;
    const int xcd = blk & 7;
    const int r2 = blk >> 3;            // 0..95
    const int rt = r2 / 6;              // 0..15
    const int cz = r2 % 6;
    const int sel = cz >> 1;            // 0..2
    const int colbase = (cz & 1) * 128;
    const int rowbase0 = (xcd * 16 + rt) * 128;   // disjoint 2048-row slab per XCD

    const float* bias = sel == 0 ? bq : sel == 1 ? bk : bv;
    const float qs = sel == 0 ? 1.44269504088896f / scale[0] : 1.0f;  // log2e/scale into Q
    const int tid = threadIdx.x;
    const int wave = tid >> 6, lane = tid & 63;
    const int l31 = lane & 31, l5 = lane >> 5;
    const int tg = (rowbase0 >> 5) + wave;        // global 32-row tile index

    // stage W rows [colbase, +128) -> LDS (linear DMA, swizzle pre-applied)
    {
        const u16* wsrc = wall + sel * 65536 + colbase * 256;
#pragma unroll
        for (int j = 0; j < 16; j++) {
            const int i = wave * 16 + j;           // 64 x 1KB chunks
            dma16(wsrc + i * 512 + lane * 8, Ws + i * 512);
        }
    }
    asm volatile("s_waitcnt vmcnt(0)" ::: "memory");
    __syncthreads();

    f32x16 acc[4];
#pragma unroll
    for (int cb = 0; cb < 4; cb++)
#pragma unroll
        for (int j = 0; j < 16; j++) acc[cb][j] = 0.f;

    const u16* ap = xp + tg * 8192 + l5 * 256 + l31 * 8;     // coalesced 1KB/instr
    const int sw = l31 & 7;

    // prefetch ALL x fragments upfront (64 VGPRs): back-to-back issue, single
    // exposed latency; MFMA loop then runs load-free.
    bf8v af[16];
#pragma unroll
    for (int kk = 0; kk < 16; kk++)
        af[kk] = *(const bf8v*)(ap + kk * 512);

    if (sel < 2) {
        // swapped: D[row=out-col(R)][col=n(l31)]
#pragma unroll
        for (int kk = 0; kk < 16; kk++) {
            const int co = ((kk * 2 + l5) ^ sw) * 8;
#pragma unroll
            for (int cb = 0; cb < 4; cb++) {
                bf8v bfr = *(const bf8v*)(Ws + (cb * 32 + l31) * 256 + co);
                acc[cb] = __builtin_amdgcn_mfma_f32_32x32x16_bf16(bfr, af[kk], acc[cb], 0, 0, 0);
            }
        }
        // epilogue: lane=n-row l31; reg r=4q+i -> col e = colb + 8q + 4*l5 + i
        u16* base = (sel == 0 ? qp : kp) + tg * 8192;
#pragma unroll
        for (int cb = 0; cb < 4; cb++) {
            const int colb = colbase + cb * 32;
#pragma unroll
            for (int q = 0; q < 4; q++) {
                const float4 b4 = *(const float4*)(bias + colb + 8 * q + 4 * l5);
                const float v0 = (acc[cb][4 * q + 0] + b4.x) * qs;
                const float v1 = (acc[cb][4 * q + 1] + b4.y) * qs;
                const float v2 = (acc[cb][4 * q + 2] + b4.z) * qs;
                const float v3 = (acc[cb][4 * q + 3] + b4.w) * qs;
                uint2 o2 = { cvtpk(v0, v1), cvtpk(v2, v3) };
                *(uint2*)(base + ((colb >> 3) + q) * 256 + l31 * 8 + 4 * l5) = o2;
            }
        }
    } else {
        // V: original order, D[row=n(R)][col=d(l31)]
#pragma unroll
        for (int kk = 0; kk < 16; kk++) {
            const int co = ((kk * 2 + l5) ^ sw) * 8;
#pragma unroll
            for (int cb = 0; cb < 4; cb++) {
                bf8v bfr = *(const bf8v*)(Ws + (cb * 32 + l31) * 256 + co);
                acc[cb] = __builtin_amdgcn_mfma_f32_32x32x16_bf16(af[kk], bfr, acc[cb], 0, 0, 0);
            }
        }
        // epilogue: reg r=4q+i -> n-row R = 8q + 4*l5 + i -> q*2048 + d0*8 + 4*l5 + i
        u16* base = vp + tg * 8192;
#pragma unroll
        for (int cb = 0; cb < 4; cb++) {
            const int colb = colbase + cb * 32;
            const float bc = bias[colb + l31];
            const int d0 = colb + l31;
#pragma unroll
            for (int q = 0; q < 4; q++) {
                const float v0 = acc[cb][4 * q + 0] + bc;
                const float v1 = acc[cb][4 * q + 1] + bc;
                const float v2 = acc[cb][4 * q + 2] + bc;
                const float v3 = acc[cb][4 * q + 3] + bc;
                uint2 o2 = { cvtpk(v0, v1), cvtpk(v2, v3) };
                *(uint2*)(base + q * 2048 + d0 * 8 + 4 * l5) = o2;
            }
        }
    }
}

// ---------------- flash attention: phase-fused MFMA pipeline, in-register P ----
// grid 512 (XCD-swizzled), block 256 = 4 waves x 32 q-rows. Bc=32, D=256, S=4.
// Q arrives pre-scaled by log2e/scale, so P = exp2(c0+c1) directly.
// Per iter: [vmcnt(0); barrier; DMA V(it+1),K(it+2) at prio 0];
//   setprio(1): phase A QK(it+1) swapped dual 8-deep chains; phase B PV(it)
//   16 MFMAs source-interleaved with exp2 of P(it+1); setprio(0).
//   (T5 regime: 2 independent blocks/CU at different phases.)
//   l-sum: VALU tree (replaces ls-MFMAs); partner half added at epilogue.
//   tail: 8 cvt_pk + 4 permlane32_swap rebuild pf0/pf1 A-frags in-register.
// K prefetched 2 ahead, V 1 ahead; 1 barrier/iter.
__global__ __launch_bounds__(256, 2) void flash_attn(
    const u16* __restrict__ qp_, const u16* __restrict__ kp_, const u16* __restrict__ vp_,
    u16* __restrict__ Opb, float* __restrict__ ml)
{
    __shared__ u16 Ks[2 * 8192];   // [buf][c(32)][kv(32)][8]
    __shared__ u16 Vs[2 * 8192];   // [buf][kvc(4)][d(256)][8]

    const int tid = threadIdx.x;
    const int wave = tid >> 6, lane = tid & 63;
    const int l31 = lane & 31, l5 = lane >> 5;

    const int blk = blockIdx.x;
    const int slot = blk >> 3;
    const int g = (blk & 7) * 2 + (slot >> 5);   // (b,s) group; matches proj's XCD slabs
    const int qtile = slot & 31;
    const int b = g >> 2, s = g & 3;
    const int qbase = qtile * 128 + wave * 32;

    // Q frags from packed layout (coalesced); used as MFMA *B* operand (same
    // register layout as A: lane -> (index=l31, k=8*l5+j))
    bf8v qf[16];
    {
        const u16* qp = qp_ + (b * 128 + qtile * 4 + wave) * 8192 + l31 * 8;
#pragma unroll
        for (int kk = 0; kk < 16; kk++)
            qf[kk] = *(const bf8v*)(qp + (kk * 2 + l5) * 256);
    }

    f32x16 o[8];
#pragma unroll
    for (int i = 0; i < 8; i++)
#pragma unroll
        for (int j = 0; j < 16; j++) o[i][j] = 0.f;
    float lsum = 0.f;

    const u16* kbase = kp_ + (b * 128 + s * 32) * 8192;
    const u16* vbase = vp_ + (b * 128 + s * 32) * 8192;

    // prologue: K0 (all 4 chunks FIRST so vmcnt(8) == K0 landed), then V0, K1
#pragma unroll
    for (int j = 0; j < 4; j++) {
        const int i = wave * 4 + j;
        dma16(kbase + i * 512 + lane * 8, Ks + i * 512);
    }
#pragma unroll
    for (int j = 0; j < 4; j++) {
        const int i = wave * 4 + j;
        dma16(vbase + i * 512 + lane * 8, Vs + i * 512);
    }
#pragma unroll
    for (int j = 0; j < 4; j++) {
        const int i = wave * 4 + j;
        dma16(kbase + 8192 + i * 512 + lane * 8, Ks + 8192 + i * 512);
    }
    asm volatile("s_waitcnt vmcnt(8)" ::: "memory");
    asm volatile("s_barrier" ::: "memory");

    // QK(0) swapped -> P(0) A-frags in-register
    bf8v pf0, pf1;
    {
        f32x16 c0, c1;
#pragma unroll
        for (int j = 0; j < 16; j++) { c0[j] = 0.f; c1[j] = 0.f; }
#pragma unroll
        for (int j = 0; j < 8; j++) {
            bf8v kf0 = *(const bf8v*)(Ks + (j * 2 + l5) * 256 + l31 * 8);
            c0 = __builtin_amdgcn_mfma_f32_32x32x16_bf16(kf0, qf[j], c0, 0, 0, 0);
            bf8v kf1 = *(const bf8v*)(Ks + ((8 + j) * 2 + l5) * 256 + l31 * 8);
            c1 = __builtin_amdgcn_mfma_f32_32x32x16_bf16(kf1, qf[8 + j], c1, 0, 0, 0);
        }
        float e[16];
#pragma unroll
        for (int r = 0; r < 16; r++)
            e[r] = __builtin_amdgcn_exp2f(c0[r] + c1[r]);
        {
            float s0 = (e[0] + e[1]) + (e[2] + e[3]);
            float s1 = (e[4] + e[5]) + (e[6] + e[7]);
            float s2 = (e[8] + e[9]) + (e[10] + e[11]);
            float s3 = (e[12] + e[13]) + (e[14] + e[15]);
            lsum += (s0 + s1) + (s2 + s3);
        }
        u32 pA = cvtpk(e[0], e[1]), pB = cvtpk(e[2], e[3]);
        u32 pC = cvtpk(e[4], e[5]), pD = cvtpk(e[6], e[7]);
        plswap(pA, pC); plswap(pB, pD);
        u32 pE = cvtpk(e[8], e[9]),  pF = cvtpk(e[10], e[11]);
        u32 pG = cvtpk(e[12], e[13]), pH = cvtpk(e[14], e[15]);
        plswap(pE, pG); plswap(pF, pH);
        union { uint4 u; bf8v v; } u0, u1;
        u0.u = (uint4){pA, pB, pC, pD};
        u1.u = (uint4){pE, pF, pG, pH};
        pf0 = u0.v; pf1 = u1.v;
    }

#pragma unroll 1
    for (int it = 0; it < 31; it++) {
        const int buf = it & 1;
        asm volatile("s_waitcnt vmcnt(0)" ::: "memory");  // V(it), K(it+1) landed
        asm volatile("s_barrier" ::: "memory");           // visible; old bufs free
        {
            const u16* vt_ = vbase + (it + 1) * 8192;
#pragma unroll
            for (int j = 0; j < 4; j++) {
                const int i = wave * 4 + j;
                dma16(vt_ + i * 512 + lane * 8, Vs + (buf ^ 1) * 8192 + i * 512);
            }
            if (it < 30) {
                const u16* kt_ = kbase + (it + 2) * 8192;
#pragma unroll
                for (int j = 0; j < 4; j++) {
                    const int i = wave * 4 + j;
                    dma16(kt_ + i * 512 + lane * 8, Ks + buf * 8192 + i * 512);
                }
            }
        }
        // ---- phase A: QK(it+1) swapped, dual 8-deep accumulator chains
        __builtin_amdgcn_s_setprio(1);
        const u16* Kb_ = Ks + (buf ^ 1) * 8192;
        f32x16 c0, c1;
#pragma unroll
        for (int j = 0; j < 16; j++) { c0[j] = 0.f; c1[j] = 0.f; }
#pragma unroll
        for (int j = 0; j < 8; j++) {
            bf8v kf0 = *(const bf8v*)(Kb_ + (j * 2 + l5) * 256 + l31 * 8);
            c0 = __builtin_amdgcn_mfma_f32_32x32x16_bf16(kf0, qf[j], c0, 0, 0, 0);
            bf8v kf1 = *(const bf8v*)(Kb_ + ((8 + j) * 2 + l5) * 256 + l31 * 8);
            c1 = __builtin_amdgcn_mfma_f32_32x32x16_bf16(kf1, qf[8 + j], c1, 0, 0, 0);
        }
        // ---- phase B: PV(it) MFMAs interleaved with exp2 of P(it+1)
        const u16* Vb_ = Vs + buf * 8192;
        float e[16];
#pragma unroll
        for (int j = 0; j < 8; j++) {
            bf8v vf0 = *(const bf8v*)(Vb_ + (l5 * 256 + j * 32 + l31) * 8);
            o[j] = __builtin_amdgcn_mfma_f32_32x32x16_bf16(pf0, vf0, o[j], 0, 0, 0);
            e[2 * j] = __builtin_amdgcn_exp2f(c0[2 * j] + c1[2 * j]);
            bf8v vf1 = *(const bf8v*)(Vb_ + ((2 + l5) * 256 + j * 32 + l31) * 8);
            o[j] = __builtin_amdgcn_mfma_f32_32x32x16_bf16(pf1, vf1, o[j], 0, 0, 0);
            e[2 * j + 1] = __builtin_amdgcn_exp2f(c0[2 * j + 1] + c1[2 * j + 1]);
        }
        __builtin_amdgcn_s_setprio(0);
        // l-sum of P(it+1) in VALU (replaces 2 ls-MFMAs), prio 0
        {
            float s0 = (e[0] + e[1]) + (e[2] + e[3]);
            float s1 = (e[4] + e[5]) + (e[6] + e[7]);
            float s2 = (e[8] + e[9]) + (e[10] + e[11]);
            float s3 = (e[12] + e[13]) + (e[14] + e[15]);
            lsum += (s0 + s1) + (s2 + s3);
        }
        // ---- tail: build P(it+1) A-frags in-register (no LDS roundtrip)
        {
            u32 pA = cvtpk(e[0], e[1]), pB = cvtpk(e[2], e[3]);
            u32 pC = cvtpk(e[4], e[5]), pD = cvtpk(e[6], e[7]);
            plswap(pA, pC); plswap(pB, pD);
            u32 pE = cvtpk(e[8], e[9]),  pF = cvtpk(e[10], e[11]);
            u32 pG = cvtpk(e[12], e[13]), pH = cvtpk(e[14], e[15]);
            plswap(pE, pG); plswap(pF, pH);
            union { uint4 u; bf8v v; } u0, u1;
            u0.u = (uint4){pA, pB, pC, pD};
            u1.u = (uint4){pE, pF, pG, pH};
            pf0 = u0.v; pf1 = u1.v;
        }
    }

    // tail: PV(31)
    asm volatile("s_waitcnt vmcnt(0)" ::: "memory");
    asm volatile("s_barrier" ::: "memory");
    {
        const u16* Vb_ = Vs + 8192;   // V(31) in buf 1
        __builtin_amdgcn_s_setprio(1);
#pragma unroll
        for (int j = 0; j < 8; j++) {
            bf8v vf0 = *(const bf8v*)(Vb_ + (l5 * 256 + j * 32 + l31) * 8);
            o[j] = __builtin_amdgcn_mfma_f32_32x32x16_bf16(pf0, vf0, o[j], 0, 0, 0);
            bf8v vf1 = *(const bf8v*)(Vb_ + ((2 + l5) * 256 + j * 32 + l31) * 8);
            o[j] = __builtin_amdgcn_mfma_f32_32x32x16_bf16(pf1, vf1, o[j], 0, 0, 0);
        }
        __builtin_amdgcn_s_setprio(0);
    }

    // epilogue: unnormalized O in bf16 + l (m==0 everywhere)
    const int rowg = s * 16384 + b * 4096 + qbase;
    u16* ob = Opb + (size_t)rowg * 256;
#pragma unroll
    for (int nb = 0; nb < 8; nb++)
#pragma unroll
        for (int r = 0; r < 16; r++) {
            const int R = (r & 3) + 8 * (r >> 2) + 4 * l5;
            ob[R * 256 + nb * 32 + l31] = f2bf(o[nb][r]);
        }
    // l: add partner half-lane (lane +-32) via permlane32_swap, write per q-row
    {
        u32 a = __float_as_uint(lsum), b2 = a;
        plswap(a, b2);
        const float tot = lsum + __uint_as_float(l5 ? a : b2);
        if (l5 == 0) ml[rowg + l31] = tot;
    }
}

// ---------------- combine partials (m==0: denom = sum of l) ----------------
// grid 2048, block 256 = 8 rows/block; 16 B/lane loads (uint4 = 8 bf16).
__global__ __launch_bounds__(256) void combine(
    const u16* __restrict__ Opb, const float* __restrict__ ml, float* __restrict__ out)
{
    const int row = blockIdx.x * 8 + (threadIdx.x >> 5);
    const int l32 = threadIdx.x & 31;
    const float denom = ml[row] + ml[16384 + row] + ml[32768 + row] + ml[49152 + row];
    float a0 = 0.f, a1 = 0.f, a2 = 0.f, a3 = 0.f, a4 = 0.f, a5 = 0.f, a6 = 0.f, a7 = 0.f;
#pragma unroll
    for (int si = 0; si < 4; si++) {
        u16x8 v = *(const u16x8*)(Opb + ((size_t)si * 16384 + row) * 256 + l32 * 8);
        a0 += bf2f(v[0]); a1 += bf2f(v[1]); a2 += bf2f(v[2]); a3 += bf2f(v[3]);
        a4 += bf2f(v[4]); a5 += bf2f(v[5]); a6 += bf2f(v[6]); a7 += bf2f(v[7]);
    }
    const float inv = 1.0f / denom;
    float4 o0 = { a0 * inv, a1 * inv, a2 * inv, a3 * inv };
    float4 o1 = { a4 * inv, a5 * inv, a6 * inv, a7 * inv };
    float* op = out + (size_t)row * 256 + l32 * 8;
    *(float4*)op = o0;
    *(float4*)(op + 4) = o1;
}

extern "C" void kernel_launch(void* const* d_in, const int* in_sizes, int n_in,
                              void* d_out, int out_size, void* d_ws, size_t ws_size,
                              hipStream_t stream) {
    const float* x     = (const float*)d_in[0];
    const float* Wq    = (const float*)d_in[1];
    const float* bq    = (const float*)d_in[2];
    const float* Wk    = (const float*)d_in[3];
    const float* bk    = (const float*)d_in[4];
    const float* Wv    = (const float*)d_in[5];
    const float* bv    = (const float*)d_in[6];
    const float* scale = (const float*)d_in[7];
    float* out = (float*)d_out;

    char* ws = (char*)d_ws;
    u16* xp   = (u16*)ws;                        // 8 MB packed x
    u16* qp   = (u16*)(ws + (8u  << 20));        // 8 MB packed Q (pre-scaled)
    u16* kp   = (u16*)(ws + (16u << 20));        // 8 MB packed K
    u16* vp   = (u16*)(ws + (24u << 20));        // 8 MB packed V
    u16* wall = (u16*)(ws + (32u << 20));        // 3 x 128 KB bf16 W (swizzled)
    u16* Opb  = (u16*)(ws + (34u << 20));        // 4 x 8 MB bf16 partials
    float* ml = (float*)(ws + (66u << 20));      // 4 x 64 KB l-sums

    cvt_all<<<2144, 256, 0, stream>>>(x, Wq, Wk, Wv, xp, wall);
    qkv_proj<<<768, 256, 0, stream>>>(xp, wall, bq, bk, bv, scale, qp, kp, vp);
    flash_attn<<<512, 256, 0, stream>>>(qp, kp, vp, Opb, ml);
    combine<<<2048, 256, 0, stream>>>(Opb, ml, out);
}